// Round 5
// baseline (292.199 us; speedup 1.0000x reference)
//
#include <hip/hip_runtime.h>
#include <cstdint>
#include <cstddef>

// Dual attention (channel attention), B=16 S=512 D=1024 H=16 dk=64.
// Round 5: fuse the f32->f16 input pack INTO the projection GEMM staging
// (regular dwordx4 loads + v_cvt + ds_write_b128 into the same XOR-swizzled
// LDS layout) -- removes ~150 MB HBM round-trip and the 45us pack of q/k/v.
// pack now converts weights only. Pv stored f16 (err ~5e-4 through Wo GEMM).
// softmax folded into mix kernel (one fewer launch).
// Pipeline:
//   1. pack_w: f32 -> f16 (Wq,Wk,Wv,Wo) + zero scores
//   2. gemm3 (z=3): P{q,k,v}16 = f16(x@W^T+b), A staged from f32 with cvt
//   3. scores[b,i,j] = sum_{s,c} Pq16[b,s,64i+c]*Pk16[b,s,64j+c]  (MFMA)
//   4. mix: per-block softmax(0.25*scores) -> Mm = I+beta*attn; attn -> d_out
//      (written by 16 designated blocks); xmix = f16(Mm @ Pv16 blocks)
//   5. out = f16 GEMM(xmix, Wo^T) + bo -> d_out (f32)
// mask (d_in[3]) and adj (d_in[4]) are unused by the reference.

#define DIM 1024

typedef _Float16 f16_t;
typedef _Float16 f16x4_t __attribute__((ext_vector_type(4)));
typedef _Float16 f16x8_t __attribute__((ext_vector_type(8)));
typedef float    f32x4_t __attribute__((ext_vector_type(4)));

__device__ __forceinline__ void async_ld16(const void* g, void* l) {
    __builtin_amdgcn_global_load_lds((const __attribute__((address_space(1))) void*)g,
                                     (__attribute__((address_space(3))) void*)l,
                                     16, 0, 0);
}

// ---------------------------------------------------------------- pack_w
// Weights only: Wq,Wk,Wv,Wo each 262144 float4 units => 1048576 units;
// tail 4096 floats zero the scores accumulator. Grid 4112 blocks.
__global__ __launch_bounds__(256) void pack_w_kernel(
    const float* __restrict__ Wq, const float* __restrict__ Wk,
    const float* __restrict__ Wv, const float* __restrict__ Wo,
    f16_t* __restrict__ Bq, f16_t* __restrict__ Bk,
    f16_t* __restrict__ Bv, f16_t* __restrict__ Bo,
    float* __restrict__ scores)
{
    const int u = blockIdx.x * 256 + threadIdx.x;
    if (u >= 1048576) {            // tail: zero scores accumulator
        scores[u - 1048576] = 0.f;
        return;
    }
    const float* src; f16_t* dst; int i;
    if (u < 262144)      { src = Wq; dst = Bq; i = u; }
    else if (u < 524288) { src = Wk; dst = Bk; i = u - 262144; }
    else if (u < 786432) { src = Wv; dst = Bv; i = u - 524288; }
    else                 { src = Wo; dst = Bo; i = u - 786432; }
    float4 s = ((const float4*)src)[i];
    f16x4_t h;
    h[0] = (f16_t)s.x; h[1] = (f16_t)s.y; h[2] = (f16_t)s.z; h[3] = (f16_t)s.w;
    ((f16x4_t*)dst)[i] = h;
}

// ---------------------------------------------------------------- gemm3
// C16[m,n] = f16( sum_k A[m,k]*B[n,k] + bias[n] ). A f32 [8192,1024] (raw
// input), staged with in-register f32->f16 cvt + ds_write_b128; B f16
// weights via global_load_lds. LDS layout XOR-swizzled in 16B units:
// LDS(row, u) = global(row, u ^ (row&7)); writes land on all 32 banks
// (bank = ((u^r)*4+..) mod 32 spans all groups as r varies), reads as before.
struct Gemm3Args {
    const float* A[3];
    const f16_t* B[3];
    const float* bias[3];
    f16_t*       C16[3];
};

__global__ __launch_bounds__(256) void gemm3(Gemm3Args args)
{
    __shared__ __align__(16) f16_t As[128 * 64];
    __shared__ __align__(16) f16_t Bs[128 * 64];

    const int z = blockIdx.z;
    const float* __restrict__ A  = args.A[z];
    const f16_t* __restrict__ B  = args.B[z];
    const float* __restrict__ bias = args.bias[z];
    f16_t* __restrict__ C16 = args.C16[z];

    const int tid  = threadIdx.x;
    const int lane = tid & 63;
    const int w    = tid >> 6;
    const int tileM = blockIdx.x * 128;
    const int tileN = blockIdx.y * 128;
    const int wm = (w & 1) << 6;
    const int wn = (w >> 1) << 6;

    f32x4_t acc[4][4];
#pragma unroll
    for (int i = 0; i < 4; ++i)
#pragma unroll
        for (int j = 0; j < 4; ++j)
            acc[i][j] = (f32x4_t){0.f, 0.f, 0.f, 0.f};

    const int srow = lane >> 3;                       // staging row in 8-row chunk
    const int u8   = lane & 7;                        // LDS 16B unit index
    const int gcol = ((u8 ^ srow) << 3);              // swizzled global col (elems)
    const int arow = lane & 15;                       // mfma frag row/col
    const int sx   = lane & 7;                        // reader swizzle (= row&7)
    const int kqu  = lane >> 4;                       // frag k 16B-unit (0..3)

    for (int kt = 0; kt < 16; ++kt) {
        const int k0 = kt << 6;
        // A: f32 loads (swizzled source cols -> linear-by-lane LDS units)
        float4 a0[4], a1[4];
#pragma unroll
        for (int t = 0; t < 4; ++t) {
            const int row = (w << 5) + (t << 3) + srow;
            const float* src = A + (size_t)(tileM + row) * DIM + k0 + gcol;
            a0[t] = *(const float4*)(src);
            a1[t] = *(const float4*)(src + 4);
        }
        // B: f16 weights, async direct-to-LDS (global col swizzled)
#pragma unroll
        for (int t = 0; t < 4; ++t) {
            const int rowb = (w << 5) + (t << 3);     // wave-uniform chunk base
            async_ld16(B + (size_t)(tileN + rowb + srow) * DIM + k0 + gcol,
                       (void*)(Bs + rowb * 64));
        }
        // A: cvt + LDS write
#pragma unroll
        for (int t = 0; t < 4; ++t) {
            const int row = (w << 5) + (t << 3) + srow;
            f16x8_t h;
            h[0] = (f16_t)a0[t].x; h[1] = (f16_t)a0[t].y;
            h[2] = (f16_t)a0[t].z; h[3] = (f16_t)a0[t].w;
            h[4] = (f16_t)a1[t].x; h[5] = (f16_t)a1[t].y;
            h[6] = (f16_t)a1[t].z; h[7] = (f16_t)a1[t].w;
            *(f16x8_t*)(As + row * 64 + (u8 << 3)) = h;
        }
        __syncthreads();
#pragma unroll
        for (int kk = 0; kk < 2; ++kk) {              // two 16B-unit groups
            const int cu = ((kk << 2) + kqu) ^ sx;    // swizzled LDS column unit
            f16x8_t af[4], bfv[4];
#pragma unroll
            for (int mt = 0; mt < 4; ++mt)
                af[mt] = *(const f16x8_t*)(As + (wm + (mt << 4) + arow) * 64 + (cu << 3));
#pragma unroll
            for (int nt = 0; nt < 4; ++nt)
                bfv[nt] = *(const f16x8_t*)(Bs + (wn + (nt << 4) + arow) * 64 + (cu << 3));
#pragma unroll
            for (int mt = 0; mt < 4; ++mt)
#pragma unroll
                for (int nt = 0; nt < 4; ++nt)
                    acc[mt][nt] = __builtin_amdgcn_mfma_f32_16x16x32_f16(
                        af[mt], bfv[nt], acc[mt][nt], 0, 0, 0);
        }
        __syncthreads();
    }

    // C/D layout: col = lane&15, row = (lane>>4)*4 + reg
    const int rq = (lane >> 4) << 2;
#pragma unroll
    for (int nt = 0; nt < 4; ++nt) {
        const int col = tileN + wn + (nt << 4) + arow;
        const float bv = bias[col];
#pragma unroll
        for (int mt = 0; mt < 4; ++mt) {
            const int row = tileM + wm + (mt << 4) + rq;
#pragma unroll
            for (int r = 0; r < 4; ++r)
                C16[(size_t)(row + r) * DIM + col] = (f16_t)(acc[mt][nt][r] + bv);
        }
    }
}

// ---------------------------------------------------------------- gemm_out
// out[m,n] = sum_k xmix[m,k]*Bo[n,k] + bo[n], f32 out. All-f16 async staging.
__global__ __launch_bounds__(256) void gemm_out(
    const f16_t* __restrict__ A, const f16_t* __restrict__ B,
    const float* __restrict__ bias, float* __restrict__ C)
{
    __shared__ __align__(16) f16_t As[128 * 64];
    __shared__ __align__(16) f16_t Bs[128 * 64];

    const int tid  = threadIdx.x;
    const int lane = tid & 63;
    const int w    = tid >> 6;
    const int tileM = blockIdx.x * 128;
    const int tileN = blockIdx.y * 128;
    const int wm = (w & 1) << 6;
    const int wn = (w >> 1) << 6;

    f32x4_t acc[4][4];
#pragma unroll
    for (int i = 0; i < 4; ++i)
#pragma unroll
        for (int j = 0; j < 4; ++j)
            acc[i][j] = (f32x4_t){0.f, 0.f, 0.f, 0.f};

    const int srow = lane >> 3;
    const int scol = ((lane & 7) ^ (lane >> 3)) << 3;
    const int arow = lane & 15;
    const int sx   = lane & 7;
    const int kqu  = lane >> 4;

    for (int kt = 0; kt < 16; ++kt) {
        const int k0 = kt << 6;
#pragma unroll
        for (int t = 0; t < 4; ++t) {
            const int row = (w << 5) + (t << 3);
            async_ld16(A + (size_t)(tileM + row + srow) * DIM + k0 + scol,
                       (void*)(As + row * 64));
            async_ld16(B + (size_t)(tileN + row + srow) * DIM + k0 + scol,
                       (void*)(Bs + row * 64));
        }
        __syncthreads();
#pragma unroll
        for (int kk = 0; kk < 2; ++kk) {
            const int cu = ((kk << 2) + kqu) ^ sx;
            f16x8_t af[4], bfv[4];
#pragma unroll
            for (int mt = 0; mt < 4; ++mt)
                af[mt] = *(const f16x8_t*)(As + (wm + (mt << 4) + arow) * 64 + (cu << 3));
#pragma unroll
            for (int nt = 0; nt < 4; ++nt)
                bfv[nt] = *(const f16x8_t*)(Bs + (wn + (nt << 4) + arow) * 64 + (cu << 3));
#pragma unroll
            for (int mt = 0; mt < 4; ++mt)
#pragma unroll
                for (int nt = 0; nt < 4; ++nt)
                    acc[mt][nt] = __builtin_amdgcn_mfma_f32_16x16x32_f16(
                        af[mt], bfv[nt], acc[mt][nt], 0, 0, 0);
        }
        __syncthreads();
    }

    const int rq = (lane >> 4) << 2;
#pragma unroll
    for (int nt = 0; nt < 4; ++nt) {
        const int col = tileN + wn + (nt << 4) + arow;
        const float bv = bias[col];
#pragma unroll
        for (int mt = 0; mt < 4; ++mt) {
            const int row = tileM + wm + (mt << 4) + rq;
#pragma unroll
            for (int r = 0; r < 4; ++r)
                C[(size_t)(row + r) * DIM + col] = acc[mt][nt][r] + bv;
        }
    }
}

// ---------------------------------------------------------------- scores
// scores[b,i,j] = sum_n Qf[b,i,n] Kf[b,j,n]. MFMA 16x16x32 per 32-c chunk.
// Grid (16 batches, 32 slices); wave w owns s = slice*16+w*4..+3.
__global__ __launch_bounds__(256) void scores_kernel(
    const f16_t* __restrict__ Pq16, const f16_t* __restrict__ Pk16,
    float* __restrict__ scores)
{
    __shared__ float red[4][256];
    const int b = blockIdx.x;
    const int lane = threadIdx.x & 63;
    const int w = threadIdx.x >> 6;
    const int m  = lane & 15;              // i (A rows) / j (B rows)
    const int q8 = (lane >> 4) << 3;       // k-offset within 32-chunk

    f32x4_t acc = (f32x4_t){0.f, 0.f, 0.f, 0.f};
    const int s0 = blockIdx.y * 16 + w * 4;
#pragma unroll
    for (int ss = 0; ss < 4; ++ss) {
        const size_t rb = (size_t)(b * 512 + s0 + ss) * DIM;
        const f16_t* qrow = Pq16 + rb;
        const f16_t* krow = Pk16 + rb;
#pragma unroll
        for (int c0 = 0; c0 < 64; c0 += 32) {
            f16x8_t af = *(const f16x8_t*)(qrow + m * 64 + c0 + q8);
            f16x8_t bf = *(const f16x8_t*)(krow + m * 64 + c0 + q8);
            acc = __builtin_amdgcn_mfma_f32_16x16x32_f16(af, bf, acc, 0, 0, 0);
        }
    }
    // C/D: col(j) = lane&15, row(i) = (lane>>4)*4 + r
    const int rq = (lane >> 4) << 2;
#pragma unroll
    for (int r = 0; r < 4; ++r)
        red[w][(rq + r) * 16 + m] = acc[r];
    __syncthreads();
    const int t = threadIdx.x;
    const float sum = red[0][t] + red[1][t] + red[2][t] + red[3][t];
    atomicAdd(&scores[b * 256 + t], sum);
}

// ---------------------------------------------------------------- mix (+softmax)
// Per block (batch b fixed): threads 0..15 compute softmax row i of
// 0.25*scores[b], write attn to d_out if designated block, build
// Mm = I + beta*attn in LDS. Then xmix[r,64i+c] = f16(sum_j Mm[i,j]*Pv16[r,64j+c]).
// 1024 blocks x 8 rows.
__global__ __launch_bounds__(256) void mix_kernel(
    const float* __restrict__ scores, const float* __restrict__ beta_p,
    const f16_t* __restrict__ Pv16,
    float* __restrict__ attn_out, f16_t* __restrict__ xmix)
{
    __shared__ float Msh[256];
    const int rbase = blockIdx.x * 8;
    const int b = rbase >> 9;
    const int t = threadIdx.x;
    if (t < 16) {
        const float beta = beta_p[0];
        float s[16];
        float mx = -1e30f;
#pragma unroll
        for (int j = 0; j < 16; ++j) {
            s[j] = scores[b * 256 + t * 16 + j] * 0.25f;   // 1/sqrt(h), h=16
            mx = fmaxf(mx, s[j]);
        }
        float sum = 0.f;
#pragma unroll
        for (int j = 0; j < 16; ++j) { s[j] = __expf(s[j] - mx); sum += s[j]; }
        const float inv = 1.f / sum;
        const bool write_attn = (rbase & 511) == 0;
#pragma unroll
        for (int j = 0; j < 16; ++j) {
            float a = s[j] * inv;
            if (write_attn) attn_out[b * 256 + t * 16 + j] = a;
            Msh[t * 16 + j] = beta * a + ((j == t) ? 1.f : 0.f);
        }
    }
    __syncthreads();
    const int w = t >> 6;
    const int lane = t & 63;
#pragma unroll
    for (int rr = 0; rr < 2; ++rr) {
        const int r = rbase + w * 2 + rr;
        const f16_t* vrow = Pv16 + (size_t)r * DIM;
        float v[16];
#pragma unroll
        for (int j = 0; j < 16; ++j) v[j] = (float)vrow[j * 64 + lane];
#pragma unroll
        for (int i = 0; i < 16; ++i) {
            float x = 0.f;
#pragma unroll
            for (int j = 0; j < 16; ++j) x += Msh[i * 16 + j] * v[j];
            xmix[(size_t)r * DIM + i * 64 + lane] = (f16_t)x;
        }
    }
}

// ---------------------------------------------------------------- launch
extern "C" void kernel_launch(void* const* d_in, const int* in_sizes, int n_in,
                              void* d_out, int out_size, void* d_ws, size_t ws_size,
                              hipStream_t stream)
{
    (void)in_sizes; (void)n_in; (void)out_size; (void)ws_size;
    const float* q    = (const float*)d_in[0];
    const float* k    = (const float*)d_in[1];
    const float* v    = (const float*)d_in[2];
    // d_in[3] mask, d_in[4] adj: unused by reference
    const float* Wq   = (const float*)d_in[5];
    const float* bq   = (const float*)d_in[6];
    const float* Wk   = (const float*)d_in[7];
    const float* bk   = (const float*)d_in[8];
    const float* Wv   = (const float*)d_in[9];
    const float* bv   = (const float*)d_in[10];
    const float* Wo   = (const float*)d_in[11];
    const float* bo   = (const float*)d_in[12];
    const float* beta = (const float*)d_in[13];

    float* out  = (float*)d_out;                     // [8192,1024]
    float* attn = (float*)d_out + 8388608;           // [16,16,16]

    char* p = (char*)d_ws;
    auto take = [&](size_t n) -> char* {
        char* cur = p; p += (n + 255) & ~(size_t)255; return cur;
    };
    f16_t* Bq = (f16_t*)take(2097152);
    f16_t* Bk = (f16_t*)take(2097152);
    f16_t* Bv = (f16_t*)take(2097152);
    f16_t* Bo = (f16_t*)take(2097152);
    f16_t* Pq16 = (f16_t*)take(16777216);
    f16_t* Pk16 = (f16_t*)take(16777216);
    f16_t* Pv16 = (f16_t*)take(16777216);
    f16_t* xmix = (f16_t*)take(16777216);
    float* scores = (float*)take(16384);

    pack_w_kernel<<<4112, 256, 0, stream>>>(Wq, Wk, Wv, Wo,
                                            Bq, Bk, Bv, Bo, scores);

    Gemm3Args ga;
    ga.A[0] = q;  ga.A[1] = k;  ga.A[2] = v;
    ga.B[0] = Bq; ga.B[1] = Bk; ga.B[2] = Bv;
    ga.bias[0] = bq; ga.bias[1] = bk; ga.bias[2] = bv;
    ga.C16[0] = Pq16; ga.C16[1] = Pk16; ga.C16[2] = Pv16;
    gemm3<<<dim3(64, 8, 3), 256, 0, stream>>>(ga);

    scores_kernel<<<dim3(16, 32), 256, 0, stream>>>(Pq16, Pk16, scores);
    mix_kernel<<<1024, 256, 0, stream>>>(scores, beta, Pv16, attn, xmix);
    gemm_out<<<dim3(64, 8), 256, 0, stream>>>(xmix, Bo, bo, out);
}